// Round 2
// baseline (5519.564 us; speedup 1.0000x reference)
//
#include <hip/hip_runtime.h>
#include <hip/hip_bf16.h>

#define N_NODES 100000
#define S_SAMP 2
#define G_GRAPH 8
#define E_EDGES 400000
#define MID 256
#define NLAYER 4
#define IN_CH 265
#define KPRE 272                    // 265 padded to mult of 16 (zero-filled)

typedef unsigned short u16;
typedef unsigned int u32;

__device__ __forceinline__ float b2f(u16 u) {
    union { u32 i; float f; } x; x.i = ((u32)u) << 16; return x.f;
}
__device__ __forceinline__ u16 f2b(float f) {
    __hip_bfloat16 h = __float2bfloat16(f);
    return *reinterpret_cast<u16*>(&h);
}

// ---------------------------------------------------------------- features (per s)
__global__ void build_xin_k(const float* __restrict__ xf,
                            const float* __restrict__ dimf,
                            const float* __restrict__ layf,
                            const float* __restrict__ tilef,
                            const float* __restrict__ opemb,
                            const int* __restrict__ opcode,
                            const int* __restrict__ batch,
                            int s, u16* __restrict__ xin) {
    int n = blockIdx.x;
    int opc = opcode[n];
    int g = batch[n];
    u16* row = xin + (size_t)n * KPRE;
    for (int c = threadIdx.x; c < KPRE; c += blockDim.x) {
        float v = 0.0f;
        if (c < 53)       v = xf[(size_t)n * 53 + c];
        else if (c < 85)  v = opemb[opc * 32 + (c - 53)];
        else if (c < 223) v = dimf[(size_t)n * 138 + (c - 85)];
        else if (c < 247) v = layf[((size_t)n * S_SAMP + s) * 24 + (c - 223)];
        else if (c < 265) v = tilef[((size_t)g * S_SAMP + s) * 18 + (c - 247)];
        row[c] = f2b(v);
    }
}

// ---------------------------------------------------------------- weight packing
// Wl/Wr: [L][256][256] bf16, cols 0:128 = conv(fwd), 128:256 = rev
__global__ void pack_w_k(const float* __restrict__ cWl, const float* __restrict__ rWl,
                         const float* __restrict__ cWr, const float* __restrict__ rWr,
                         const float* __restrict__ cb,  const float* __restrict__ rb,
                         u16* __restrict__ Wl, u16* __restrict__ Wr,
                         float* __restrict__ bc) {
    int idx = blockIdx.x * blockDim.x + threadIdx.x;
    if (idx < NLAYER * 256 * 256) {
        int l = idx >> 16;
        int r = idx & 65535;
        int k = r >> 8;
        int j = r & 255;
        float vl, vr;
        if (j < 128) {
            vl = cWl[((size_t)l * 256 + k) * 128 + j];
            vr = cWr[((size_t)l * 256 + k) * 128 + j];
        } else {
            vl = rWl[((size_t)l * 256 + k) * 128 + (j - 128)];
            vr = rWr[((size_t)l * 256 + k) * 128 + (j - 128)];
        }
        Wl[idx] = f2b(vl);
        Wr[idx] = f2b(vr);
    }
    if (idx < NLAYER * 256) {
        int l = idx >> 8;
        int j = idx & 255;
        bc[idx] = (j < 128) ? cb[l * 128 + j] : rb[l * 128 + (j - 128)];
    }
}

__global__ void pack_pre_k(const float* __restrict__ preW, u16* __restrict__ preWb) {
    int idx = blockIdx.x * blockDim.x + threadIdx.x;   // KPRE*256
    if (idx >= KPRE * 256) return;
    int k = idx >> 8;
    int j = idx & 255;
    preWb[idx] = (k < IN_CH) ? f2b(preW[(size_t)k * 256 + j]) : (u16)0;
}

// ---------------------------------------------------------------- degrees + CSR
__global__ void deg_k(const int* __restrict__ ei, int* __restrict__ degF,
                      int* __restrict__ degR) {
    int e = blockIdx.x * blockDim.x + threadIdx.x;
    if (e < E_EDGES) {
        atomicAdd(&degF[ei[E_EDGES + e]], 1);  // in-degree at tgt
        atomicAdd(&degR[ei[e]], 1);            // in-degree at src (reverse)
    }
}

// single-block exclusive scan over both degree arrays → rowptr[N+1]
__global__ __launch_bounds__(1024) void scan_k(const int* __restrict__ degF,
                                               const int* __restrict__ degR,
                                               int* __restrict__ rpF,
                                               int* __restrict__ rpR) {
    __shared__ int buf[1024];
    __shared__ int carry;
    for (int pass = 0; pass < 2; pass++) {
        const int* deg = pass ? degR : degF;
        int* rp = pass ? rpR : rpF;
        if (threadIdx.x == 0) carry = 0;
        __syncthreads();
        for (int base = 0; base < N_NODES; base += 1024) {
            int i = base + threadIdx.x;
            int v = (i < N_NODES) ? deg[i] : 0;
            buf[threadIdx.x] = v;
            __syncthreads();
            for (int off = 1; off < 1024; off <<= 1) {
                int t = (threadIdx.x >= off) ? buf[threadIdx.x - off] : 0;
                __syncthreads();
                buf[threadIdx.x] += t;
                __syncthreads();
            }
            int excl = buf[threadIdx.x] - v;
            int total = buf[1023];
            if (i < N_NODES) rp[i] = carry + excl;
            __syncthreads();
            if (threadIdx.x == 0) carry += total;
            __syncthreads();
        }
        if (threadIdx.x == 0) rp[N_NODES] = carry;
        __syncthreads();
    }
}

__global__ void inv_cursor_k(const int* __restrict__ degF, const int* __restrict__ degR,
                             const int* __restrict__ rpF, const int* __restrict__ rpR,
                             float* __restrict__ invF, float* __restrict__ invR,
                             int* __restrict__ curF, int* __restrict__ curR) {
    int i = blockIdx.x * blockDim.x + threadIdx.x;
    if (i < N_NODES) {
        invF[i] = 1.0f / fmaxf((float)degF[i], 1.0f);
        invR[i] = 1.0f / fmaxf((float)degR[i], 1.0f);
        curF[i] = rpF[i];
        curR[i] = rpR[i];
    }
}

__global__ void fill_k(const int* __restrict__ ei, int* __restrict__ curF,
                       int* __restrict__ curR, int* __restrict__ colF,
                       int* __restrict__ colR) {
    int e = blockIdx.x * blockDim.x + threadIdx.x;
    if (e < E_EDGES) {
        int s = ei[e], t = ei[E_EDGES + e];
        int p = atomicAdd(&curF[t], 1);
        colF[p] = s;          // fwd: tgt gathers from src
        int q = atomicAdd(&curR[s], 1);
        colR[q] = t;          // rev: src gathers from tgt
    }
}

// ---------------------------------------------------------------- GEMM (bf16 in, fp32 acc, bf16 out)
// C[M,256] = act(A[M,K]) @ B[K,256] + bias.  64x64 tile, 256 thr, 4x4/thread.
template <bool RELU_A>
__global__ __launch_bounds__(256) void mm_k(const u16* __restrict__ A, int lda, int K, int M,
                                            const u16* __restrict__ B,
                                            const float* __restrict__ bias,
                                            u16* __restrict__ C) {
    __shared__ float As[64][17];
    __shared__ float Bs[16][65];
    int tid = threadIdx.x;
    int tx = tid & 15, ty = tid >> 4;
    int rowBase = blockIdx.x * 64;
    int colBase = blockIdx.y * 64;
    float acc[4][4] = {};
    for (int k0 = 0; k0 < K; k0 += 16) {
        {   // A tile: 64 rows x 16 k ; thread t loads 4 bf16 (8 B)
            int r = tid >> 2, kk = (tid & 3) * 4;
            int row = rowBase + r;
            float v0 = 0, v1 = 0, v2 = 0, v3 = 0;
            if (row < M) {
                const u16* p = A + (size_t)row * lda + k0 + kk;
                ushort4 u = *reinterpret_cast<const ushort4*>(p);
                v0 = b2f(u.x); v1 = b2f(u.y); v2 = b2f(u.z); v3 = b2f(u.w);
                if (RELU_A) {
                    v0 = fmaxf(v0, 0.f); v1 = fmaxf(v1, 0.f);
                    v2 = fmaxf(v2, 0.f); v3 = fmaxf(v3, 0.f);
                }
            }
            As[r][kk] = v0; As[r][kk + 1] = v1; As[r][kk + 2] = v2; As[r][kk + 3] = v3;
        }
        {   // B tile: 16 k x 64 cols ; thread t loads 4 bf16
            int kk = tid >> 4, c = (tid & 15) * 4;
            const u16* p = B + (size_t)(k0 + kk) * 256 + colBase + c;
            ushort4 u = *reinterpret_cast<const ushort4*>(p);
            Bs[kk][c] = b2f(u.x); Bs[kk][c + 1] = b2f(u.y);
            Bs[kk][c + 2] = b2f(u.z); Bs[kk][c + 3] = b2f(u.w);
        }
        __syncthreads();
        #pragma unroll
        for (int kk = 0; kk < 16; kk++) {
            float a[4], b[4];
            #pragma unroll
            for (int i = 0; i < 4; i++) a[i] = As[ty + 16 * i][kk];
            #pragma unroll
            for (int j = 0; j < 4; j++) b[j] = Bs[kk][tx + 16 * j];
            #pragma unroll
            for (int i = 0; i < 4; i++)
                #pragma unroll
                for (int j = 0; j < 4; j++) acc[i][j] += a[i] * b[j];
        }
        __syncthreads();
    }
    #pragma unroll
    for (int i = 0; i < 4; i++) {
        int row = rowBase + ty + 16 * i;
        if (row < M) {
            #pragma unroll
            for (int j = 0; j < 4; j++) {
                int col = colBase + tx + 16 * j;
                C[(size_t)row * 256 + col] = f2b(acc[i][j] + bias[col]);
            }
        }
    }
}

// ---------------------------------------------------------------- aggregation (CSR gather)
// One wave per node: Xn[n,0:128]   += invF[n] * sum_{src in colF[n]} H[src,0:128]
//                    Xn[n,128:256] += invR[n] * sum_{tgt in colR[n]} H[tgt,128:256]
__global__ __launch_bounds__(256) void agg_k(const int* __restrict__ rpF,
                                             const int* __restrict__ colF,
                                             const int* __restrict__ rpR,
                                             const int* __restrict__ colR,
                                             const float* __restrict__ invF,
                                             const float* __restrict__ invR,
                                             const u16* __restrict__ H,
                                             u16* __restrict__ Xn) {
    int n = (blockIdx.x * blockDim.x + threadIdx.x) >> 6;
    int lane = threadIdx.x & 63;
    if (n >= N_NODES) return;
    float aF0 = 0, aF1 = 0, aR0 = 0, aR1 = 0;
    int b0 = rpF[n], e0 = rpF[n + 1];
    for (int j = b0; j < e0; j++) {
        int src = colF[j];
        ushort2 u = *reinterpret_cast<const ushort2*>(H + (size_t)src * 256 + 2 * lane);
        aF0 += b2f(u.x); aF1 += b2f(u.y);
    }
    int b1 = rpR[n], e1 = rpR[n + 1];
    for (int j = b1; j < e1; j++) {
        int t = colR[j];
        ushort2 u = *reinterpret_cast<const ushort2*>(H + (size_t)t * 256 + 128 + 2 * lane);
        aR0 += b2f(u.x); aR1 += b2f(u.y);
    }
    float iF = invF[n], iR = invR[n];
    u16* xp = Xn + (size_t)n * 256;
    ushort2 x0 = *reinterpret_cast<ushort2*>(xp + 2 * lane);
    ushort2 x1 = *reinterpret_cast<ushort2*>(xp + 128 + 2 * lane);
    x0.x = f2b(b2f(x0.x) + aF0 * iF);
    x0.y = f2b(b2f(x0.y) + aF1 * iF);
    x1.x = f2b(b2f(x1.x) + aR0 * iR);
    x1.y = f2b(b2f(x1.y) + aR1 * iR);
    *reinterpret_cast<ushort2*>(xp + 2 * lane) = x0;
    *reinterpret_cast<ushort2*>(xp + 128 + 2 * lane) = x1;
}

// ---------------------------------------------------------------- pool + head
__global__ void out_init_k(float* __restrict__ out, const float* __restrict__ headb) {
    int i = threadIdx.x;
    if (i < G_GRAPH * S_SAMP) out[i] = headb[0];
}

// per-(s, layer): out[g*S + s] += sum_n relu(X[n,:]) . headW[woff:woff+256]
__global__ __launch_bounds__(256) void pool_k(const u16* __restrict__ X,
                                              const float* __restrict__ headW, int woff,
                                              const int* __restrict__ batch,
                                              float* __restrict__ out, int s) {
    __shared__ float wsm[256];
    __shared__ float part[G_GRAPH];
    int tid = threadIdx.x;
    wsm[tid] = headW[woff + tid];
    if (tid < G_GRAPH) part[tid] = 0.0f;
    __syncthreads();
    int lane = tid & 63;
    int gw = blockIdx.x * 4 + (tid >> 6);
    int nw = gridDim.x * 4;
    for (int n = gw; n < N_NODES; n += nw) {
        const u16* p = X + (size_t)n * 256;
        float acc = 0.0f;
        #pragma unroll
        for (int j = 0; j < 4; j++) {
            int c = lane + 64 * j;
            acc += fmaxf(b2f(p[c]), 0.0f) * wsm[c];
        }
        #pragma unroll
        for (int off = 32; off > 0; off >>= 1) acc += __shfl_down(acc, off);
        if (lane == 0) atomicAdd(&part[batch[n]], acc);
    }
    __syncthreads();
    if (tid < G_GRAPH) atomicAdd(&out[tid * S_SAMP + s], part[tid]);
}

// ---------------------------------------------------------------- launch
extern "C" void kernel_launch(void* const* d_in, const int* in_sizes, int n_in,
                              void* d_out, int out_size, void* d_ws, size_t ws_size,
                              hipStream_t stream) {
    const float* x_feat      = (const float*)d_in[0];
    const float* dim_feat    = (const float*)d_in[1];
    const float* layout_feat = (const float*)d_in[2];
    const float* tile_feat   = (const float*)d_in[3];
    const float* opemb       = (const float*)d_in[4];
    const float* preW        = (const float*)d_in[5];
    const float* preb        = (const float*)d_in[6];
    const float* convWl      = (const float*)d_in[7];
    const float* convWr      = (const float*)d_in[8];
    const float* convb       = (const float*)d_in[9];
    const float* revWl       = (const float*)d_in[10];
    const float* revWr       = (const float*)d_in[11];
    const float* revb        = (const float*)d_in[12];
    const float* headW       = (const float*)d_in[13];
    const float* headb       = (const float*)d_in[14];
    const int*   node_opcode = (const int*)d_in[15];
    const int*   batch       = (const int*)d_in[16];
    const int*   edge_index  = (const int*)d_in[17];
    float* out = (float*)d_out;

    // byte-based workspace allocator (total ~165 MB)
    char* ws = (char*)d_ws;
    size_t off = 0;
    auto alloc = [&](size_t nbytes) {
        char* p = ws + off;
        off += (nbytes + 255) & ~(size_t)255;
        return p;
    };
    u16* XA    = (u16*)alloc((size_t)N_NODES * 256 * 2);
    u16* XB    = (u16*)alloc((size_t)N_NODES * 256 * 2);
    u16* XinH  = (u16*)alloc((size_t)N_NODES * KPRE * 2);  // Xin, then reused as H
    u16* Wl    = (u16*)alloc((size_t)NLAYER * 65536 * 2);
    u16* Wr    = (u16*)alloc((size_t)NLAYER * 65536 * 2);
    u16* preWb = (u16*)alloc((size_t)KPRE * 256 * 2);
    float* bc  = (float*)alloc(NLAYER * 256 * 4);
    float* bz  = (float*)alloc(256 * 4);
    int* degF  = (int*)alloc(N_NODES * 4);
    int* degR  = (int*)alloc(N_NODES * 4);
    int* rpF   = (int*)alloc((N_NODES + 1) * 4);
    int* rpR   = (int*)alloc((N_NODES + 1) * 4);
    int* curF  = (int*)alloc(N_NODES * 4);
    int* curR  = (int*)alloc(N_NODES * 4);
    int* colF  = (int*)alloc(E_EDGES * 4);
    int* colR  = (int*)alloc(E_EDGES * 4);
    float* invF = (float*)alloc(N_NODES * 4);
    float* invR = (float*)alloc(N_NODES * 4);

    hipMemsetAsync(degF, 0, N_NODES * 4, stream);
    hipMemsetAsync(degR, 0, N_NODES * 4, stream);
    hipMemsetAsync(bz, 0, 256 * 4, stream);

    pack_w_k<<<(NLAYER * 65536 + 255) / 256, 256, 0, stream>>>(
        convWl, revWl, convWr, revWr, convb, revb, Wl, Wr, bc);
    pack_pre_k<<<(KPRE * 256 + 255) / 256, 256, 0, stream>>>(preW, preWb);
    deg_k<<<(E_EDGES + 255) / 256, 256, 0, stream>>>(edge_index, degF, degR);
    scan_k<<<1, 1024, 0, stream>>>(degF, degR, rpF, rpR);
    inv_cursor_k<<<(N_NODES + 255) / 256, 256, 0, stream>>>(
        degF, degR, rpF, rpR, invF, invR, curF, curR);
    fill_k<<<(E_EDGES + 255) / 256, 256, 0, stream>>>(edge_index, curF, curR, colF, colR);

    out_init_k<<<1, 64, 0, stream>>>(out, headb);

    dim3 mmGrid((N_NODES + 63) / 64, 4);
    for (int s = 0; s < S_SAMP; s++) {
        build_xin_k<<<N_NODES, 256, 0, stream>>>(
            x_feat, dim_feat, layout_feat, tile_feat, opemb, node_opcode, batch, s, XinH);
        // X0 = Xin @ preW + preb  (stored pre-relu)
        mm_k<false><<<mmGrid, 256, 0, stream>>>(XinH, KPRE, KPRE, N_NODES, preWb, preb, XA);

        u16* ins[NLAYER]  = {XA, XB, XA, XB};
        u16* outs[NLAYER] = {XB, XA, XB, XA};
        for (int l = 0; l < NLAYER; l++) {
            const u16* Wrl = Wr + (size_t)l * 65536;
            const u16* Wll = Wl + (size_t)l * 65536;
            const float* bl = bc + (size_t)l * 256;
            // X_next = relu(x) @ Wr_cat + b_cat
            mm_k<true><<<mmGrid, 256, 0, stream>>>(ins[l], 256, 256, N_NODES, Wrl, bl, outs[l]);
            // H = relu(x) @ Wl_cat
            mm_k<true><<<mmGrid, 256, 0, stream>>>(ins[l], 256, 256, N_NODES, Wll, bz, XinH);
            // X_next += CSR-gathered, inv-scaled messages
            agg_k<<<(N_NODES * 64 + 255) / 256, 256, 0, stream>>>(
                rpF, colF, rpR, colR, invF, invR, XinH, outs[l]);
            if (l == 2) pool_k<<<512, 256, 0, stream>>>(outs[l], headW, 0, batch, out, s);
            if (l == 3) pool_k<<<512, 256, 0, stream>>>(outs[l], headW, 256, batch, out, s);
        }
    }
}

// Round 4
// 2393.519 us; speedup vs baseline: 2.3060x; 2.3060x over previous
//
#include <hip/hip_runtime.h>
#include <hip/hip_bf16.h>

#define N_NODES 100000
#define S_SAMP 2
#define G_GRAPH 8
#define E_EDGES 400000
#define NLAYER 4
#define IN_CH 265
#define KPRE 288                    // 265 padded to mult of 96 (zero-filled)
#define NROWT ((N_NODES + 63) / 64) // 1563
#define NB1 ((N_NODES + 1023) / 1024) // 98 scan blocks

typedef unsigned short u16;
typedef unsigned int u32;
typedef short bf16x8 __attribute__((ext_vector_type(8)));
typedef float f32x4 __attribute__((ext_vector_type(4)));

__device__ __forceinline__ float b2f(u16 u) {
    union { u32 i; float f; } x; x.i = ((u32)u) << 16; return x.f;
}
__device__ __forceinline__ u16 f2b(float f) {
    __hip_bfloat16 h = __float2bfloat16(f);
    return *reinterpret_cast<u16*>(&h);
}
__device__ __forceinline__ u16 relu_b(u16 v) { return (v & 0x8000u) ? (u16)0 : v; }

// ---------------------------------------------------------------- features (per s)
__global__ void build_xin_k(const float* __restrict__ xf,
                            const float* __restrict__ dimf,
                            const float* __restrict__ layf,
                            const float* __restrict__ tilef,
                            const float* __restrict__ opemb,
                            const int* __restrict__ opcode,
                            const int* __restrict__ batch,
                            int s, u16* __restrict__ xin) {
    int n = blockIdx.x;
    int opc = opcode[n];
    int g = batch[n];
    u16* row = xin + (size_t)n * KPRE;
    for (int c = threadIdx.x; c < KPRE; c += blockDim.x) {
        float v = 0.0f;
        if (c < 53)       v = xf[(size_t)n * 53 + c];
        else if (c < 85)  v = opemb[opc * 32 + (c - 53)];
        else if (c < 223) v = dimf[(size_t)n * 138 + (c - 85)];
        else if (c < 247) v = layf[((size_t)n * S_SAMP + s) * 24 + (c - 223)];
        else if (c < 265) v = tilef[((size_t)g * S_SAMP + s) * 18 + (c - 247)];
        row[c] = f2b(v);
    }
}

// ---------------------------------------------------------------- weight packing (transposed)
// Wt: [L][512][256] bf16.  n<256 -> Wr_cat (X_next), n>=256 -> Wl_cat (H).
// Within each 256: col<128 = conv, col>=128 = rev.   bcat: [L][512] (upper 256 zero)
__global__ void pack_w_k(const float* __restrict__ cWl, const float* __restrict__ rWl,
                         const float* __restrict__ cWr, const float* __restrict__ rWr,
                         const float* __restrict__ cb,  const float* __restrict__ rb,
                         u16* __restrict__ Wt, float* __restrict__ bcat) {
    int idx = blockIdx.x * blockDim.x + threadIdx.x;   // L*512*256
    if (idx < NLAYER * 512 * 256) {
        int l = idx >> 17;
        int r = idx & 131071;
        int j = r >> 8;            // output col 0..511
        int k = r & 255;
        int jj = j & 255;
        int half = j >> 8;         // 0 = Wr, 1 = Wl
        int sub = jj >> 7;         // 0 = conv, 1 = rev
        int col = jj & 127;
        const float* src = half ? (sub ? rWl : cWl) : (sub ? rWr : cWr);
        Wt[idx] = f2b(src[((size_t)l * 256 + k) * 128 + col]);
    }
    if (idx < NLAYER * 512) {
        int l = idx >> 9;
        int j = idx & 511;
        float v = 0.0f;
        if (j < 256) v = (j < 128) ? cb[l * 128 + j] : rb[l * 128 + (j - 128)];
        bcat[idx] = v;
    }
}

// preWt: [256][KPRE] bf16 (transposed, zero-padded K)
__global__ void pack_pre_k(const float* __restrict__ preW, u16* __restrict__ preWt) {
    int idx = blockIdx.x * blockDim.x + threadIdx.x;
    if (idx >= 256 * KPRE) return;
    int j = idx / KPRE;
    int k = idx - j * KPRE;
    preWt[idx] = (k < IN_CH) ? f2b(preW[(size_t)k * 256 + j]) : (u16)0;
}

// ---------------------------------------------------------------- degrees + CSR
__global__ void deg_k(const int* __restrict__ ei, int* __restrict__ degF,
                      int* __restrict__ degR) {
    int e = blockIdx.x * blockDim.x + threadIdx.x;
    if (e < E_EDGES) {
        atomicAdd(&degF[ei[E_EDGES + e]], 1);
        atomicAdd(&degR[ei[e]], 1);
    }
}

// pass 1: per-block exclusive scan of 1024, block totals to bsum[y*NB1+x]
__global__ __launch_bounds__(1024) void scan1_k(const int* __restrict__ degF,
                                                const int* __restrict__ degR,
                                                int* __restrict__ rpF,
                                                int* __restrict__ rpR,
                                                int* __restrict__ bsum) {
    const int* deg = blockIdx.y ? degR : degF;
    int* rp = blockIdx.y ? rpR : rpF;
    __shared__ int buf[1024];
    int i = blockIdx.x * 1024 + threadIdx.x;
    int v = (i < N_NODES) ? deg[i] : 0;
    buf[threadIdx.x] = v;
    __syncthreads();
    for (int off = 1; off < 1024; off <<= 1) {
        int t = (threadIdx.x >= off) ? buf[threadIdx.x - off] : 0;
        __syncthreads();
        buf[threadIdx.x] += t;
        __syncthreads();
    }
    if (i < N_NODES) rp[i] = buf[threadIdx.x] - v;
    if (threadIdx.x == 1023) bsum[blockIdx.y * NB1 + blockIdx.x] = buf[1023];
}

// pass 2: scan the NB1 block sums (both arrays in one block), write totals to rp[N]
__global__ __launch_bounds__(256) void scan2_k(int* __restrict__ bsum,
                                               int* __restrict__ rpF,
                                               int* __restrict__ rpR) {
    __shared__ int buf[2][128];
    int half = threadIdx.x >> 7;
    int t = threadIdx.x & 127;
    int v = (t < NB1) ? bsum[half * NB1 + t] : 0;
    buf[half][t] = v;
    __syncthreads();
    for (int off = 1; off < 128; off <<= 1) {
        int x = (t >= off) ? buf[half][t - off] : 0;
        __syncthreads();
        buf[half][t] += x;
        __syncthreads();
    }
    if (t < NB1) bsum[half * NB1 + t] = buf[half][t] - v;
    if (t == NB1) (half ? rpR : rpF)[N_NODES] = buf[half][NB1 - 1];
}

// pass 3: add block offsets
__global__ void scan3_k(const int* __restrict__ bsum, int* __restrict__ rpF,
                        int* __restrict__ rpR) {
    int* rp = blockIdx.y ? rpR : rpF;
    int i = blockIdx.x * 1024 + threadIdx.x;
    if (i < N_NODES) rp[i] += bsum[blockIdx.y * NB1 + blockIdx.x];
}

__global__ void inv_cursor_k(const int* __restrict__ degF, const int* __restrict__ degR,
                             const int* __restrict__ rpF, const int* __restrict__ rpR,
                             float* __restrict__ invF, float* __restrict__ invR,
                             int* __restrict__ curF, int* __restrict__ curR) {
    int i = blockIdx.x * blockDim.x + threadIdx.x;
    if (i < N_NODES) {
        invF[i] = 1.0f / fmaxf((float)degF[i], 1.0f);
        invR[i] = 1.0f / fmaxf((float)degR[i], 1.0f);
        curF[i] = rpF[i];
        curR[i] = rpR[i];
    }
}

__global__ void fill_k(const int* __restrict__ ei, int* __restrict__ curF,
                       int* __restrict__ curR, int* __restrict__ colF,
                       int* __restrict__ colR) {
    int e = blockIdx.x * blockDim.x + threadIdx.x;
    if (e < E_EDGES) {
        int s = ei[e], t = ei[E_EDGES + e];
        colF[atomicAdd(&curF[t], 1)] = s;
        colR[atomicAdd(&curR[s], 1)] = t;
    }
}

// ---------------------------------------------------------------- MFMA GEMM
// C[M,N] = act(A[M,K]) @ B[K,N] + bias;  B given transposed Bt[N][K].
// 64x64 tile per block (256 thr, 4 waves; wave w handles rows w*16..w*16+15).
// KC: compile-time K-chunk, multiple of 32 (fragment reads stay < KC).
// Cols<256 -> C0 (+bias), cols>=256 -> C1.
template <bool RELU_A, int KC>
__global__ __launch_bounds__(256) void mm_mfma_k(const u16* __restrict__ A, int K, int M,
                                                 const u16* __restrict__ Bt,
                                                 const float* __restrict__ bias,
                                                 u16* __restrict__ C0,
                                                 u16* __restrict__ C1) {
    constexpr int KP = KC + 8;             // padded LDS stride (shorts)
    __shared__ u16 As[64 * 136];
    __shared__ u16 Bs[64 * 136];
    static_assert(KP <= 136, "LDS stride overflow");
    int tid = threadIdx.x;
    int colBase = blockIdx.x * 64;
    int rowBase = blockIdx.y * 64;
    int wave = tid >> 6;
    int lane = tid & 63;
    int quad = lane >> 4;
    int l16 = lane & 15;

    f32x4 acc[4] = {};
    constexpr int KC8 = KC >> 3;           // ushort8 chunks per row
    constexpr int NCH = 64 * KC8;

    for (int k0 = 0; k0 < K; k0 += KC) {
        // stage A chunk (64 rows x KC) with optional relu
        #pragma unroll
        for (int c = tid; c < NCH; c += 256) {
            int r = c / KC8;
            int kk = (c - r * KC8) << 3;
            int row = rowBase + r;
            ushort4 a = {0, 0, 0, 0}, b = {0, 0, 0, 0};
            if (row < M) {
                const u16* p = A + (size_t)row * K + k0 + kk;
                a = ((const ushort4*)p)[0];
                b = ((const ushort4*)p)[1];
                if (RELU_A) {
                    a.x = relu_b(a.x); a.y = relu_b(a.y); a.z = relu_b(a.z); a.w = relu_b(a.w);
                    b.x = relu_b(b.x); b.y = relu_b(b.y); b.z = relu_b(b.z); b.w = relu_b(b.w);
                }
            }
            u16* d = As + r * KP + kk;
            ((ushort4*)d)[0] = a;
            ((ushort4*)d)[1] = b;
        }
        // stage Bt chunk (64 cols x KC) — rows of Bt are contiguous
        #pragma unroll
        for (int c = tid; c < NCH; c += 256) {
            int r = c / KC8;
            int kk = (c - r * KC8) << 3;
            const u16* p = Bt + (size_t)(colBase + r) * K + k0 + kk;
            ushort4 a = ((const ushort4*)p)[0];
            ushort4 b = ((const ushort4*)p)[1];
            u16* d = Bs + r * KP + kk;
            ((ushort4*)d)[0] = a;
            ((ushort4*)d)[1] = b;
        }
        __syncthreads();
        #pragma unroll
        for (int k = 0; k < KC; k += 32) {
            bf16x8 af = *(const bf16x8*)(As + (wave * 16 + l16) * KP + k + quad * 8);
            #pragma unroll
            for (int cf = 0; cf < 4; cf++) {
                bf16x8 bf = *(const bf16x8*)(Bs + (cf * 16 + l16) * KP + k + quad * 8);
                acc[cf] = __builtin_amdgcn_mfma_f32_16x16x32_bf16(af, bf, acc[cf], 0, 0, 0);
            }
        }
        __syncthreads();
    }

    // epilogue: C/D layout col=lane&15, row=quad*4+reg
    u16* dst = (colBase < 256) ? C0 : C1;
    int cb = colBase & 255;
    #pragma unroll
    for (int cf = 0; cf < 4; cf++) {
        int col = cb + cf * 16 + l16;
        float bv = bias[colBase + cf * 16 + l16];
        #pragma unroll
        for (int r = 0; r < 4; r++) {
            int row = rowBase + wave * 16 + quad * 4 + r;
            if (row < M) dst[(size_t)row * 256 + col] = f2b(acc[cf][r] + bv);
        }
    }
}

// ---------------------------------------------------------------- aggregation (CSR gather)
__global__ __launch_bounds__(256) void agg_k(const int* __restrict__ rpF,
                                             const int* __restrict__ colF,
                                             const int* __restrict__ rpR,
                                             const int* __restrict__ colR,
                                             const float* __restrict__ invF,
                                             const float* __restrict__ invR,
                                             const u16* __restrict__ H,
                                             u16* __restrict__ Xn) {
    int n = (blockIdx.x * blockDim.x + threadIdx.x) >> 6;
    int lane = threadIdx.x & 63;
    if (n >= N_NODES) return;
    float aF0 = 0, aF1 = 0, aR0 = 0, aR1 = 0;
    int b0 = rpF[n], e0 = rpF[n + 1];
    for (int j = b0; j < e0; j++) {
        int src = colF[j];
        ushort2 u = *reinterpret_cast<const ushort2*>(H + (size_t)src * 256 + 2 * lane);
        aF0 += b2f(u.x); aF1 += b2f(u.y);
    }
    int b1 = rpR[n], e1 = rpR[n + 1];
    for (int j = b1; j < e1; j++) {
        int t = colR[j];
        ushort2 u = *reinterpret_cast<const ushort2*>(H + (size_t)t * 256 + 128 + 2 * lane);
        aR0 += b2f(u.x); aR1 += b2f(u.y);
    }
    float iF = invF[n], iR = invR[n];
    u16* xp = Xn + (size_t)n * 256;
    ushort2 x0 = *reinterpret_cast<ushort2*>(xp + 2 * lane);
    ushort2 x1 = *reinterpret_cast<ushort2*>(xp + 128 + 2 * lane);
    x0.x = f2b(b2f(x0.x) + aF0 * iF);
    x0.y = f2b(b2f(x0.y) + aF1 * iF);
    x1.x = f2b(b2f(x1.x) + aR0 * iR);
    x1.y = f2b(b2f(x1.y) + aR1 * iR);
    *reinterpret_cast<ushort2*>(xp + 2 * lane) = x0;
    *reinterpret_cast<ushort2*>(xp + 128 + 2 * lane) = x1;
}

// ---------------------------------------------------------------- pool + head
__global__ void out_init_k(float* __restrict__ out, const float* __restrict__ headb) {
    int i = threadIdx.x;
    if (i < G_GRAPH * S_SAMP) out[i] = headb[0];
}

__global__ __launch_bounds__(256) void pool_k(const u16* __restrict__ X,
                                              const float* __restrict__ headW, int woff,
                                              const int* __restrict__ batch,
                                              float* __restrict__ out, int s) {
    __shared__ float wsm[256];
    __shared__ float part[G_GRAPH];
    int tid = threadIdx.x;
    wsm[tid] = headW[woff + tid];
    if (tid < G_GRAPH) part[tid] = 0.0f;
    __syncthreads();
    int lane = tid & 63;
    int gw = blockIdx.x * 4 + (tid >> 6);
    int nw = gridDim.x * 4;
    for (int n = gw; n < N_NODES; n += nw) {
        const u16* p = X + (size_t)n * 256;
        float acc = 0.0f;
        #pragma unroll
        for (int j = 0; j < 4; j++) {
            int c = lane + 64 * j;
            acc += fmaxf(b2f(p[c]), 0.0f) * wsm[c];
        }
        #pragma unroll
        for (int off = 32; off > 0; off >>= 1) acc += __shfl_down(acc, off);
        if (lane == 0) atomicAdd(&part[batch[n]], acc);
    }
    __syncthreads();
    if (tid < G_GRAPH) atomicAdd(&out[tid * S_SAMP + s], part[tid]);
}

// ---------------------------------------------------------------- launch
extern "C" void kernel_launch(void* const* d_in, const int* in_sizes, int n_in,
                              void* d_out, int out_size, void* d_ws, size_t ws_size,
                              hipStream_t stream) {
    const float* x_feat      = (const float*)d_in[0];
    const float* dim_feat    = (const float*)d_in[1];
    const float* layout_feat = (const float*)d_in[2];
    const float* tile_feat   = (const float*)d_in[3];
    const float* opemb       = (const float*)d_in[4];
    const float* preW        = (const float*)d_in[5];
    const float* preb        = (const float*)d_in[6];
    const float* convWl      = (const float*)d_in[7];
    const float* convWr      = (const float*)d_in[8];
    const float* convb       = (const float*)d_in[9];
    const float* revWl       = (const float*)d_in[10];
    const float* revWr       = (const float*)d_in[11];
    const float* revb        = (const float*)d_in[12];
    const float* headW       = (const float*)d_in[13];
    const float* headb       = (const float*)d_in[14];
    const int*   node_opcode = (const int*)d_in[15];
    const int*   batch       = (const int*)d_in[16];
    const int*   edge_index  = (const int*)d_in[17];
    float* out = (float*)d_out;

    char* ws = (char*)d_ws;
    size_t off = 0;
    auto alloc = [&](size_t nbytes) {
        char* p = ws + off;
        off += (nbytes + 255) & ~(size_t)255;
        return p;
    };
    u16* XA    = (u16*)alloc((size_t)N_NODES * 256 * 2);
    u16* XB    = (u16*)alloc((size_t)N_NODES * 256 * 2);
    u16* XinH  = (u16*)alloc((size_t)N_NODES * KPRE * 2);  // Xin, then reused as H
    u16* Wt    = (u16*)alloc((size_t)NLAYER * 512 * 256 * 2);
    u16* preWt = (u16*)alloc((size_t)256 * KPRE * 2);
    float* bcat = (float*)alloc(NLAYER * 512 * 4);
    int* degF  = (int*)alloc(N_NODES * 4);
    int* degR  = (int*)alloc(N_NODES * 4);
    int* rpF   = (int*)alloc((N_NODES + 1) * 4);
    int* rpR   = (int*)alloc((N_NODES + 1) * 4);
    int* curF  = (int*)alloc(N_NODES * 4);
    int* curR  = (int*)alloc(N_NODES * 4);
    int* colF  = (int*)alloc(E_EDGES * 4);
    int* colR  = (int*)alloc(E_EDGES * 4);
    int* bsum  = (int*)alloc(2 * NB1 * 4);
    float* invF = (float*)alloc(N_NODES * 4);
    float* invR = (float*)alloc(N_NODES * 4);

    hipMemsetAsync(degF, 0, N_NODES * 4, stream);
    hipMemsetAsync(degR, 0, N_NODES * 4, stream);

    pack_w_k<<<(NLAYER * 512 * 256 + 255) / 256, 256, 0, stream>>>(
        convWl, revWl, convWr, revWr, convb, revb, Wt, bcat);
    pack_pre_k<<<(256 * KPRE + 255) / 256, 256, 0, stream>>>(preW, preWt);
    deg_k<<<(E_EDGES + 255) / 256, 256, 0, stream>>>(edge_index, degF, degR);
    scan1_k<<<dim3(NB1, 2), 1024, 0, stream>>>(degF, degR, rpF, rpR, bsum);
    scan2_k<<<1, 256, 0, stream>>>(bsum, rpF, rpR);
    scan3_k<<<dim3(NB1, 2), 1024, 0, stream>>>(bsum, rpF, rpR);
    inv_cursor_k<<<(N_NODES + 255) / 256, 256, 0, stream>>>(
        degF, degR, rpF, rpR, invF, invR, curF, curR);
    fill_k<<<(E_EDGES + 255) / 256, 256, 0, stream>>>(edge_index, curF, curR, colF, colR);

    out_init_k<<<1, 64, 0, stream>>>(out, headb);

    for (int s = 0; s < S_SAMP; s++) {
        build_xin_k<<<N_NODES, 256, 0, stream>>>(
            x_feat, dim_feat, layout_feat, tile_feat, opemb, node_opcode, batch, s, XinH);
        // X0 = Xin @ preW + preb (stored pre-relu); KC=96 (288 = 3*96)
        mm_mfma_k<false, 96><<<dim3(4, NROWT), 256, 0, stream>>>(
            XinH, KPRE, N_NODES, preWt, preb, XA, XA);

        u16* ins[NLAYER]  = {XA, XB, XA, XB};
        u16* outs[NLAYER] = {XB, XA, XB, XA};
        for (int l = 0; l < NLAYER; l++) {
            // fused: [X_next | H] = relu(x) @ [Wr_cat | Wl_cat] + [b_cat | 0]
            mm_mfma_k<true, 128><<<dim3(8, NROWT), 256, 0, stream>>>(
                ins[l], 256, N_NODES, Wt + (size_t)l * 512 * 256,
                bcat + (size_t)l * 512, outs[l], XinH);
            agg_k<<<(N_NODES * 64 + 255) / 256, 256, 0, stream>>>(
                rpF, colF, rpR, colR, invF, invR, XinH, outs[l]);
            if (l == 2) pool_k<<<512, 256, 0, stream>>>(outs[l], headW, 0, batch, out, s);
            if (l == 3) pool_k<<<512, 256, 0, stream>>>(outs[l], headW, 256, batch, out, s);
        }
    }
}